// Round 3
// baseline (807.547 us; speedup 1.0000x reference)
//
#include <hip/hip_runtime.h>

// MHA: B=2, S=2048, D=1024, H=16, hd=64. Inputs/outputs FLOAT32 (per reference).
// Internally: f32 -> bf16 convert, MFMA bf16 GEMMs w/ fp32 accum, scalar-VALU
// flash attention with fp32 LDS tiles.
// k0: cvt x, Wqkv, Wo -> bf16 in ws
// k1: qkv = x @ Wqkv^T + bqkv -> scatter to Q/K/V [B,H,S,hd] bf16
// k2: flash attention -> vals [B,S,D] bf16
// k3: out = vals @ Wo^T + bo -> f32

typedef short short8 __attribute__((ext_vector_type(8)));
typedef unsigned short ushort8v __attribute__((ext_vector_type(8)));
typedef float floatx4 __attribute__((ext_vector_type(4)));

#define S_LEN 2048
#define D_MODEL 1024
#define N_HEADS 16
#define HEAD_DIM 64
// fp32 attention LDS tiles: stride 68 keeps every float4 access 16B-aligned
// (stride 65 broke ds_*_b128 alignment -> garbage).
#define APAD 68

__device__ inline float bf2f(unsigned int u16) {
    union { unsigned int i; float f; } v; v.i = u16 << 16; return v.f;
}
// f32 -> bf16 (RNE), bit-level.
__device__ inline unsigned short f2b(float f) {
    union { float f; unsigned int u; } v; v.f = f;
    return (unsigned short)((v.u + 0x7FFFu + ((v.u >> 16) & 1u)) >> 16);
}

// k0: convert three f32 arrays to bf16. Counts are in groups of 8 elements.
__global__ __launch_bounds__(256)
void cvt3(const float* __restrict__ s0, const float* __restrict__ s1,
          const float* __restrict__ s2,
          unsigned short* __restrict__ d0, unsigned short* __restrict__ d1,
          unsigned short* __restrict__ d2,
          int n0, int n1, int n2) {
    const int total = n0 + n1 + n2;
    for (int g = blockIdx.x * blockDim.x + threadIdx.x; g < total;
         g += gridDim.x * blockDim.x) {
        const float* s; unsigned short* d; int l;
        if (g < n0)            { s = s0; d = d0; l = g; }
        else if (g < n0 + n1)  { s = s1; d = d1; l = g - n0; }
        else                   { s = s2; d = d2; l = g - n0 - n1; }
        const float4* sp = (const float4*)s + (size_t)l * 2;
        float4 f0 = sp[0], f1 = sp[1];
        ushort8v o;
        o[0] = f2b(f0.x); o[1] = f2b(f0.y); o[2] = f2b(f0.z); o[3] = f2b(f0.w);
        o[4] = f2b(f1.x); o[5] = f2b(f1.y); o[6] = f2b(f1.z); o[7] = f2b(f1.w);
        *(ushort8v*)(d + (size_t)l * 8) = o;
    }
}

// Load 16 consecutive bf16 (as u16) from global, store 16 fp32 to LDS.
__device__ inline void stage16(const unsigned short* __restrict__ src, float* dst) {
    const uint4* sv = (const uint4*)src;
    uint4 u0 = sv[0], u1 = sv[1];
    unsigned int w[8] = {u0.x, u0.y, u0.z, u0.w, u1.x, u1.y, u1.z, u1.w};
#pragma unroll
    for (int i = 0; i < 8; i++) {
        dst[2 * i]     = bf2f(w[i] & 0xFFFFu);
        dst[2 * i + 1] = bf2f(w[i] >> 16);
    }
}

// ---------------- MFMA GEMM core: C[m,n] = sum_k A[m,k] * W[n,k] --------------
// Tile 128x128, BK=64, 256 threads = 4 waves (2x2), each wave 64x64 via 4x4 MFMAs.
// A: [M,K] bf16(u16) row-major; W: [N,K] bf16(u16) row-major; K multiple of 64.
__device__ inline void gemm_core(const unsigned short* __restrict__ A,
                                 const unsigned short* __restrict__ W,
                                 int m0, int n0, int K,
                                 unsigned short* As, unsigned short* Bs,
                                 floatx4 acc[4][4]) {
    const int tid  = threadIdx.x;
    const int lane = tid & 63;
    const int wave = tid >> 6;
    const int wm = wave >> 1, wn = wave & 1;
    const int r = lane & 15, q = lane >> 4;

    const int lrow  = tid >> 1;         // 0..127
    const int lhalf = (tid & 1) * 32;   // element offset 0 or 32

    for (int k0 = 0; k0 < K; k0 += 64) {
        __syncthreads();
        const uint4* ga = (const uint4*)(A + (size_t)(m0 + lrow) * K + k0 + lhalf);
        const uint4* gb = (const uint4*)(W + (size_t)(n0 + lrow) * K + k0 + lhalf);
        uint4* sa = (uint4*)(As + lrow * 64 + lhalf);
        uint4* sb = (uint4*)(Bs + lrow * 64 + lhalf);
#pragma unroll
        for (int i = 0; i < 4; i++) { sa[i] = ga[i]; sb[i] = gb[i]; }
        __syncthreads();
#pragma unroll
        for (int kk = 0; kk < 64; kk += 32) {
            short8 aF[4], bF[4];
#pragma unroll
            for (int t = 0; t < 4; t++)
                aF[t] = *(const short8*)(As + (wm * 64 + t * 16 + r) * 64 + kk + q * 8);
#pragma unroll
            for (int t = 0; t < 4; t++)
                bF[t] = *(const short8*)(Bs + (wn * 64 + t * 16 + r) * 64 + kk + q * 8);
#pragma unroll
            for (int i = 0; i < 4; i++)
#pragma unroll
                for (int j = 0; j < 4; j++)
                    acc[i][j] = __builtin_amdgcn_mfma_f32_16x16x32_bf16(aF[i], bF[j], acc[i][j], 0, 0, 0);
        }
    }
}

// k1: QKV projection. Grid (3072/128, 4096/128) = (24, 32).
__global__ __launch_bounds__(256)
void qkv_gemm(const unsigned short* __restrict__ x,
              const unsigned short* __restrict__ Wqkv,
              const float* __restrict__ bqkv,
              unsigned short* __restrict__ Qb,
              unsigned short* __restrict__ Kb,
              unsigned short* __restrict__ Vb) {
    __shared__ unsigned short As[128 * 64];
    __shared__ unsigned short Bs[128 * 64];
    const int lane = threadIdx.x & 63;
    const int wave = threadIdx.x >> 6;
    const int wm = wave >> 1, wn = wave & 1;
    const int r = lane & 15, q = lane >> 4;
    const int m0 = blockIdx.y * 128;
    const int n0 = blockIdx.x * 128;

    floatx4 acc[4][4] = {};
    gemm_core(x, Wqkv, m0, n0, D_MODEL, As, Bs, acc);

#pragma unroll
    for (int i = 0; i < 4; i++) {
#pragma unroll
        for (int j = 0; j < 4; j++) {
            int n = n0 + wn * 64 + j * 16 + r;            // 0..3071 = h*192 + typ*64 + d
            int h = n / 192;
            int rem = n % 192;
            int typ = rem >> 6;                            // 0=Q 1=K 2=V
            int d = rem & 63;
            unsigned short* dst = (typ == 0) ? Qb : ((typ == 1) ? Kb : Vb);
            float bv = bqkv[n];
#pragma unroll
            for (int rg = 0; rg < 4; rg++) {
                int m = m0 + wm * 64 + i * 16 + q * 4 + rg;  // 0..4095
                int b = m >> 11, s = m & 2047;
                dst[(((size_t)(b * N_HEADS + h)) * S_LEN + s) * HEAD_DIM + d] =
                    f2b(acc[i][j][rg] + bv);
            }
        }
    }
}

// k3: output projection. Grid (1024/128, 4096/128) = (8, 32). f32 output.
__global__ __launch_bounds__(256)
void out_gemm(const unsigned short* __restrict__ vals,
              const unsigned short* __restrict__ Wo,
              const float* __restrict__ bo,
              float* __restrict__ out) {
    __shared__ unsigned short As[128 * 64];
    __shared__ unsigned short Bs[128 * 64];
    const int lane = threadIdx.x & 63;
    const int wave = threadIdx.x >> 6;
    const int wm = wave >> 1, wn = wave & 1;
    const int r = lane & 15, q = lane >> 4;
    const int m0 = blockIdx.y * 128;
    const int n0 = blockIdx.x * 128;

    floatx4 acc[4][4] = {};
    gemm_core(vals, Wo, m0, n0, D_MODEL, As, Bs, acc);

#pragma unroll
    for (int i = 0; i < 4; i++) {
#pragma unroll
        for (int j = 0; j < 4; j++) {
            int n = n0 + wn * 64 + j * 16 + r;
            float bv = bo[n];
#pragma unroll
            for (int rg = 0; rg < 4; rg++) {
                int m = m0 + wm * 64 + i * 16 + q * 4 + rg;
                out[(size_t)m * D_MODEL + n] = acc[i][j][rg] + bv;
            }
        }
    }
}

// k2: flash attention, scalar VALU. Grid (S/64, B*H) = (32, 32), 256 threads.
// Thread (ty=tid>>4, tx=tid&15) owns rows ty*4..+3, cols tx*4..+3 of each 64x64 tile.
__global__ __launch_bounds__(256)
void attn_kernel(const unsigned short* __restrict__ Qb,
                 const unsigned short* __restrict__ Kb,
                 const unsigned short* __restrict__ Vb,
                 unsigned short* __restrict__ vals) {
    __shared__ float Qs[64][APAD];
    __shared__ float KVs[64][APAD];
    __shared__ float Ps[64][APAD];

    const int tid = threadIdx.x;
    const int tx = tid & 15, ty = tid >> 4;
    const int bh = blockIdx.y;           // b*16 + h
    const int b = bh >> 4, h = bh & 15;
    const int q0 = blockIdx.x * 64;

    const unsigned short* Qp = Qb + (size_t)bh * S_LEN * HEAD_DIM;
    const unsigned short* Kp = Kb + (size_t)bh * S_LEN * HEAD_DIM;
    const unsigned short* Vp = Vb + (size_t)bh * S_LEN * HEAD_DIM;

    // Load Q tile (64x64) once.
    {
        int row = tid >> 2, seg = (tid & 3) * 16;
        stage16(Qp + (size_t)(q0 + row) * HEAD_DIM + seg, &Qs[row][seg]);
    }

    float m_i[4], l_i[4], o_[4][4];
#pragma unroll
    for (int i = 0; i < 4; i++) {
        m_i[i] = -1e30f; l_i[i] = 0.f;
#pragma unroll
        for (int j = 0; j < 4; j++) o_[i][j] = 0.f;
    }
    const float scale = 0.125f;  // 1/sqrt(64)

    for (int kt = 0; kt < S_LEN; kt += 64) {
        __syncthreads();  // prior-tile PV reads done (also covers initial Q write)
        {
            int row = tid >> 2, seg = (tid & 3) * 16;
            stage16(Kp + (size_t)(kt + row) * HEAD_DIM + seg, &KVs[row][seg]);
        }
        __syncthreads();

        // scores: s[i][j] = scale * dot64(Q[ty*4+i], K[tx*4+j])
        float s_[4][4] = {};
#pragma unroll 4
        for (int kk = 0; kk < 64; kk += 4) {
            float4 kv[4];
#pragma unroll
            for (int j = 0; j < 4; j++) kv[j] = *(const float4*)&KVs[tx * 4 + j][kk];
#pragma unroll
            for (int i = 0; i < 4; i++) {
                float4 qv = *(const float4*)&Qs[ty * 4 + i][kk];
#pragma unroll
                for (int j = 0; j < 4; j++)
                    s_[i][j] += qv.x * kv[j].x + qv.y * kv[j].y + qv.z * kv[j].z + qv.w * kv[j].w;
            }
        }

        // online softmax (16-lane row groups)
#pragma unroll
        for (int i = 0; i < 4; i++) {
#pragma unroll
            for (int j = 0; j < 4; j++) s_[i][j] *= scale;
            float rm = fmaxf(fmaxf(s_[i][0], s_[i][1]), fmaxf(s_[i][2], s_[i][3]));
#pragma unroll
            for (int off = 1; off < 16; off <<= 1) rm = fmaxf(rm, __shfl_xor(rm, off, 64));
            float newm = fmaxf(m_i[i], rm);
            float alpha = __expf(m_i[i] - newm);
            float rs = 0.f;
#pragma unroll
            for (int j = 0; j < 4; j++) { s_[i][j] = __expf(s_[i][j] - newm); rs += s_[i][j]; }
#pragma unroll
            for (int off = 1; off < 16; off <<= 1) rs += __shfl_xor(rs, off, 64);
            l_i[i] = l_i[i] * alpha + rs;
            m_i[i] = newm;
#pragma unroll
            for (int j = 0; j < 4; j++) o_[i][j] *= alpha;
            *(float4*)&Ps[ty * 4 + i][tx * 4] = make_float4(s_[i][0], s_[i][1], s_[i][2], s_[i][3]);
        }
        __syncthreads();  // Ps written, K reads done -> safe to overwrite KVs
        {
            int row = tid >> 2, seg = (tid & 3) * 16;
            stage16(Vp + (size_t)(kt + row) * HEAD_DIM + seg, &KVs[row][seg]);
        }
        __syncthreads();

        // O += P @ V
#pragma unroll 4
        for (int jj = 0; jj < 64; jj += 4) {
            float4 v4[4];
#pragma unroll
            for (int u = 0; u < 4; u++) v4[u] = *(const float4*)&KVs[jj + u][tx * 4];
#pragma unroll
            for (int i = 0; i < 4; i++) {
                float4 p4 = *(const float4*)&Ps[ty * 4 + i][jj];
                o_[i][0] += p4.x * v4[0].x + p4.y * v4[1].x + p4.z * v4[2].x + p4.w * v4[3].x;
                o_[i][1] += p4.x * v4[0].y + p4.y * v4[1].y + p4.z * v4[2].y + p4.w * v4[3].y;
                o_[i][2] += p4.x * v4[0].z + p4.y * v4[1].z + p4.z * v4[2].z + p4.w * v4[3].z;
                o_[i][3] += p4.x * v4[0].w + p4.y * v4[1].w + p4.z * v4[2].w + p4.w * v4[3].w;
            }
        }
    }

    // vals[b][s][h*64 + d]  (bf16)
#pragma unroll
    for (int i = 0; i < 4; i++) {
        float inv = 1.0f / l_i[i];
        int srow = q0 + ty * 4 + i;
        size_t base = ((size_t)b * S_LEN + srow) * D_MODEL + h * HEAD_DIM + tx * 4;
#pragma unroll
        for (int j = 0; j < 4; j++)
            vals[base + j] = f2b(o_[i][j] * inv);
    }
}

extern "C" void kernel_launch(void* const* d_in, const int* in_sizes, int n_in,
                              void* d_out, int out_size, void* d_ws, size_t ws_size,
                              hipStream_t stream) {
    const float* x    = (const float*)d_in[0];   // [2,2048,1024] f32
    const float* Wqkv = (const float*)d_in[1];   // [3072,1024]   f32
    const float* bqkv = (const float*)d_in[2];   // [3072]        f32
    const float* Wo   = (const float*)d_in[3];   // [1024,1024]   f32
    const float* bo   = (const float*)d_in[4];   // [1024]        f32
    float* out = (float*)d_out;                  // [2,2048,1024] f32

    const size_t NX = 4194304, NW = 3145728, NO = 1048576;
    unsigned short* xb    = (unsigned short*)d_ws;   // bf16 x
    unsigned short* Wqkvb = xb + NX;
    unsigned short* Wob   = Wqkvb + NW;
    unsigned short* Qb    = Wob + NO;                // [B,H,S,hd] each
    unsigned short* Kb    = Qb + NX;
    unsigned short* Vb    = Kb + NX;
    unsigned short* vals  = xb;  // reuse x region after qkv_gemm (ws total ~42MB)

    cvt3<<<4096, 256, 0, stream>>>(x, Wqkv, Wo, xb, Wqkvb, Wob,
                                   (int)(NX / 8), (int)(NW / 8), (int)(NO / 8));
    qkv_gemm<<<dim3(24, 32), 256, 0, stream>>>(xb, Wqkvb, bqkv, Qb, Kb, Vb);
    attn_kernel<<<dim3(32, 32), 256, 0, stream>>>(Qb, Kb, Vb, vals);
    out_gemm<<<dim3(8, 32), 256, 0, stream>>>(vals, Wob, bo, out);
}

// Round 4
// 291.890 us; speedup vs baseline: 2.7666x; 2.7666x over previous
//
#include <hip/hip_runtime.h>

// MHA: B=2, S=2048, D=1024, H=16, hd=64. Inputs/outputs FLOAT32 (per reference).
// k0: cvt x, Wqkv, Wo -> bf16 in ws
// k1: qkv GEMM (MFMA) -> Q(*0.125) [b,h,s,d], K [b,h,s,d], V TRANSPOSED [b,h,d,s]
// k2: MFMA flash attention -> vals [B,S,D] bf16
// k3: out GEMM (MFMA) -> f32

typedef short short8 __attribute__((ext_vector_type(8)));
typedef unsigned short ushort8v __attribute__((ext_vector_type(8)));
typedef unsigned short ushort4v __attribute__((ext_vector_type(4)));
typedef float floatx4 __attribute__((ext_vector_type(4)));

#define S_LEN 2048
#define D_MODEL 1024
#define N_HEADS 16
#define HEAD_DIM 64
// bf16 LDS tiles in attn: stride 72 shorts = 144 B (16B multiple -> b128-safe;
// odd multiple of 4 words -> rows spread across banks).
#define KPAD 72

__device__ inline float bf2f(unsigned int u16) {
    union { unsigned int i; float f; } v; v.i = u16 << 16; return v.f;
}
// f32 -> bf16 (RNE), bit-level.
__device__ inline unsigned short f2b(float f) {
    union { float f; unsigned int u; } v; v.f = f;
    return (unsigned short)((v.u + 0x7FFFu + ((v.u >> 16) & 1u)) >> 16);
}

// k0: convert three f32 arrays to bf16. Counts in groups of 8 elements.
__global__ __launch_bounds__(256)
void cvt3(const float* __restrict__ s0, const float* __restrict__ s1,
          const float* __restrict__ s2,
          unsigned short* __restrict__ d0, unsigned short* __restrict__ d1,
          unsigned short* __restrict__ d2,
          int n0, int n1, int n2) {
    const int total = n0 + n1 + n2;
    for (int g = blockIdx.x * blockDim.x + threadIdx.x; g < total;
         g += gridDim.x * blockDim.x) {
        const float* s; unsigned short* d; int l;
        if (g < n0)            { s = s0; d = d0; l = g; }
        else if (g < n0 + n1)  { s = s1; d = d1; l = g - n0; }
        else                   { s = s2; d = d2; l = g - n0 - n1; }
        const float4* sp = (const float4*)s + (size_t)l * 2;
        float4 f0 = sp[0], f1 = sp[1];
        ushort8v o;
        o[0] = f2b(f0.x); o[1] = f2b(f0.y); o[2] = f2b(f0.z); o[3] = f2b(f0.w);
        o[4] = f2b(f1.x); o[5] = f2b(f1.y); o[6] = f2b(f1.z); o[7] = f2b(f1.w);
        *(ushort8v*)(d + (size_t)l * 8) = o;
    }
}

// ---------------- MFMA GEMM core: C[m,n] = sum_k A[m,k] * W[n,k] --------------
__device__ inline void gemm_core(const unsigned short* __restrict__ A,
                                 const unsigned short* __restrict__ W,
                                 int m0, int n0, int K,
                                 unsigned short* As, unsigned short* Bs,
                                 floatx4 acc[4][4]) {
    const int tid  = threadIdx.x;
    const int lane = tid & 63;
    const int wave = tid >> 6;
    const int wm = wave >> 1, wn = wave & 1;
    const int r = lane & 15, q = lane >> 4;

    const int lrow  = tid >> 1;
    const int lhalf = (tid & 1) * 32;

    for (int k0 = 0; k0 < K; k0 += 64) {
        __syncthreads();
        const uint4* ga = (const uint4*)(A + (size_t)(m0 + lrow) * K + k0 + lhalf);
        const uint4* gb = (const uint4*)(W + (size_t)(n0 + lrow) * K + k0 + lhalf);
        uint4* sa = (uint4*)(As + lrow * 64 + lhalf);
        uint4* sb = (uint4*)(Bs + lrow * 64 + lhalf);
#pragma unroll
        for (int i = 0; i < 4; i++) { sa[i] = ga[i]; sb[i] = gb[i]; }
        __syncthreads();
#pragma unroll
        for (int kk = 0; kk < 64; kk += 32) {
            short8 aF[4], bF[4];
#pragma unroll
            for (int t = 0; t < 4; t++)
                aF[t] = *(const short8*)(As + (wm * 64 + t * 16 + r) * 64 + kk + q * 8);
#pragma unroll
            for (int t = 0; t < 4; t++)
                bF[t] = *(const short8*)(Bs + (wn * 64 + t * 16 + r) * 64 + kk + q * 8);
#pragma unroll
            for (int i = 0; i < 4; i++)
#pragma unroll
                for (int j = 0; j < 4; j++)
                    acc[i][j] = __builtin_amdgcn_mfma_f32_16x16x32_bf16(aF[i], bF[j], acc[i][j], 0, 0, 0);
        }
    }
}

// k1: QKV projection. Grid (24, 32). Q scaled by 0.125 (softmax scale folded in).
// Q,K layout [b,h,s,d]; V layout [b,h,d,s] (transposed for attn B-fragments).
__global__ __launch_bounds__(256)
void qkv_gemm(const unsigned short* __restrict__ x,
              const unsigned short* __restrict__ Wqkv,
              const float* __restrict__ bqkv,
              unsigned short* __restrict__ Qb,
              unsigned short* __restrict__ Kb,
              unsigned short* __restrict__ Vb) {
    __shared__ unsigned short As[128 * 64];
    __shared__ unsigned short Bs[128 * 64];
    const int lane = threadIdx.x & 63;
    const int wave = threadIdx.x >> 6;
    const int wm = wave >> 1, wn = wave & 1;
    const int r = lane & 15, q = lane >> 4;
    const int m0 = blockIdx.y * 128;
    const int n0 = blockIdx.x * 128;

    floatx4 acc[4][4] = {};
    gemm_core(x, Wqkv, m0, n0, D_MODEL, As, Bs, acc);

#pragma unroll
    for (int i = 0; i < 4; i++) {
#pragma unroll
        for (int j = 0; j < 4; j++) {
            int n = n0 + wn * 64 + j * 16 + r;            // h*192 + typ*64 + d
            int h = n / 192;
            int rem = n % 192;
            int typ = rem >> 6;                            // 0=Q 1=K 2=V
            int d = rem & 63;
            float bv = bqkv[n];
            int m = m0 + wm * 64 + i * 16 + q * 4;         // first of 4 rows
            int b = m >> 11, s = m & 2047;
            if (typ == 2) {
                // V transposed: [b,h,d,s]; 4 consecutive s -> one 8B store
                ushort4v pk;
#pragma unroll
                for (int rg = 0; rg < 4; rg++) pk[rg] = f2b(acc[i][j][rg] + bv);
                *(ushort4v*)(Vb + ((size_t)((b * N_HEADS + h) * HEAD_DIM + d)) * S_LEN + s) = pk;
            } else {
                unsigned short* dst = (typ == 0) ? Qb : Kb;
                float sc = (typ == 0) ? 0.125f : 1.0f;
#pragma unroll
                for (int rg = 0; rg < 4; rg++)
                    dst[(((size_t)(b * N_HEADS + h)) * S_LEN + s + rg) * HEAD_DIM + d] =
                        f2b((acc[i][j][rg] + bv) * sc);
            }
        }
    }
}

// k3: output projection. Grid (8, 32). f32 output.
__global__ __launch_bounds__(256)
void out_gemm(const unsigned short* __restrict__ vals,
              const unsigned short* __restrict__ Wo,
              const float* __restrict__ bo,
              float* __restrict__ out) {
    __shared__ unsigned short As[128 * 64];
    __shared__ unsigned short Bs[128 * 64];
    const int lane = threadIdx.x & 63;
    const int wave = threadIdx.x >> 6;
    const int wm = wave >> 1, wn = wave & 1;
    const int r = lane & 15, q = lane >> 4;
    const int m0 = blockIdx.y * 128;
    const int n0 = blockIdx.x * 128;

    floatx4 acc[4][4] = {};
    gemm_core(vals, Wo, m0, n0, D_MODEL, As, Bs, acc);

#pragma unroll
    for (int i = 0; i < 4; i++) {
#pragma unroll
        for (int j = 0; j < 4; j++) {
            int n = n0 + wn * 64 + j * 16 + r;
            float bv = bo[n];
#pragma unroll
            for (int rg = 0; rg < 4; rg++) {
                int m = m0 + wm * 64 + i * 16 + q * 4 + rg;
                out[(size_t)m * D_MODEL + n] = acc[i][j][rg] + bv;
            }
        }
    }
}

// k2: MFMA flash attention. Grid (S/128=16, B*H=32), 256 threads = 4 waves.
// Wave w owns Q rows w*32..w*32+31 (2 row-tiles of 16). K-tile = 64 keys.
// QK^T: A=Q[m=q,k=d], B=K[n=key,k=d].  PV: A=P[m=q,k=key], B=Vt[n=d,k=key].
__global__ __launch_bounds__(256)
void attn_kernel(const unsigned short* __restrict__ Qb,
                 const unsigned short* __restrict__ Kb,
                 const unsigned short* __restrict__ Vg,   // [b,h,d,s]
                 unsigned short* __restrict__ vals) {
    __shared__ unsigned short Qs[128 * KPAD];
    __shared__ unsigned short Ks[64 * KPAD];
    __shared__ unsigned short Vts[64 * KPAD];
    __shared__ unsigned short Ps[128 * KPAD];

    const int tid = threadIdx.x;
    const int lane = tid & 63;
    const int wave = tid >> 6;
    const int r = lane & 15, q2 = lane >> 4;
    const int w32 = wave * 32;
    const int bh = blockIdx.y;
    const int b = bh >> 4, h = bh & 15;
    const int q0 = blockIdx.x * 128;

    const unsigned short* Qp = Qb + (size_t)bh * S_LEN * HEAD_DIM;
    const unsigned short* Kp = Kb + (size_t)bh * S_LEN * HEAD_DIM;
    const unsigned short* Vp = Vg + (size_t)bh * HEAD_DIM * S_LEN;

    // Stage Q tile (128x64) once: thread t -> row t>>1, 32-elem half (t&1).
    {
        int row = tid >> 1, off = (tid & 1) * 32;
        const uint4* g = (const uint4*)(Qp + (size_t)(q0 + row) * HEAD_DIM + off);
        uint4* sdst = (uint4*)(Qs + row * KPAD + off);
#pragma unroll
        for (int i = 0; i < 4; i++) sdst[i] = g[i];
    }

    float m_i[2][4], l_i[2][4];
    floatx4 o_acc[2][4] = {};
#pragma unroll
    for (int rt = 0; rt < 2; rt++)
#pragma unroll
        for (int reg = 0; reg < 4; reg++) { m_i[rt][reg] = -1e30f; l_i[rt][reg] = 0.f; }

    const int krow = tid >> 2, kseg = (tid & 3) * 16;

    for (int kt = 0; kt < S_LEN; kt += 64) {
        __syncthreads();  // all waves done reading Ks/Vts from previous tile
        {
            const uint4* gk = (const uint4*)(Kp + (size_t)(kt + krow) * HEAD_DIM + kseg);
            const uint4* gv = (const uint4*)(Vp + (size_t)krow * S_LEN + kt + kseg);
            uint4* sk = (uint4*)(Ks + krow * KPAD + kseg);
            uint4* sv = (uint4*)(Vts + krow * KPAD + kseg);
            sk[0] = gk[0]; sk[1] = gk[1];
            sv[0] = gv[0]; sv[1] = gv[1];
        }
        __syncthreads();

        // ---- QK^T: sp[rt][ct] = Q(32 rows) x K(64 keys), d = 64 ----
        short8 qf[2][2], kf[4][2];
#pragma unroll
        for (int rt = 0; rt < 2; rt++)
#pragma unroll
            for (int ks = 0; ks < 2; ks++)
                qf[rt][ks] = *(const short8*)(Qs + (w32 + rt * 16 + r) * KPAD + ks * 32 + q2 * 8);
#pragma unroll
        for (int ct = 0; ct < 4; ct++)
#pragma unroll
            for (int ks = 0; ks < 2; ks++)
                kf[ct][ks] = *(const short8*)(Ks + (ct * 16 + r) * KPAD + ks * 32 + q2 * 8);

        floatx4 sp[2][4] = {};
#pragma unroll
        for (int rt = 0; rt < 2; rt++)
#pragma unroll
            for (int ct = 0; ct < 4; ct++)
#pragma unroll
                for (int ks = 0; ks < 2; ks++)
                    sp[rt][ct] = __builtin_amdgcn_mfma_f32_16x16x32_bf16(qf[rt][ks], kf[ct][ks], sp[rt][ct], 0, 0, 0);

        // ---- online softmax; lane holds col=key(=r-group), rows q2*4+reg ----
#pragma unroll
        for (int rt = 0; rt < 2; rt++) {
#pragma unroll
            for (int reg = 0; reg < 4; reg++) {
                float v0 = fmaxf(fmaxf(sp[rt][0][reg], sp[rt][1][reg]),
                                 fmaxf(sp[rt][2][reg], sp[rt][3][reg]));
#pragma unroll
                for (int off = 1; off < 16; off <<= 1) v0 = fmaxf(v0, __shfl_xor(v0, off, 64));
                float nm = fmaxf(m_i[rt][reg], v0);
                float alpha = __expf(m_i[rt][reg] - nm);
                m_i[rt][reg] = nm;
                float rs = 0.f;
#pragma unroll
                for (int ct = 0; ct < 4; ct++) {
                    float e = __expf(sp[rt][ct][reg] - nm);
                    sp[rt][ct][reg] = e;
                    rs += e;
                }
#pragma unroll
                for (int off = 1; off < 16; off <<= 1) rs += __shfl_xor(rs, off, 64);
                l_i[rt][reg] = l_i[rt][reg] * alpha + rs;
#pragma unroll
                for (int dt = 0; dt < 4; dt++) o_acc[rt][dt][reg] *= alpha;
            }
        }

        // ---- P (C-layout) -> LDS [q][key] bf16 (own wave's 32 rows) ----
#pragma unroll
        for (int rt = 0; rt < 2; rt++)
#pragma unroll
            for (int ct = 0; ct < 4; ct++)
#pragma unroll
                for (int reg = 0; reg < 4; reg++)
                    Ps[(w32 + rt * 16 + q2 * 4 + reg) * KPAD + ct * 16 + r] = f2b(sp[rt][ct][reg]);
        // same-wave write->read: compiler's lgkmcnt ordering suffices, no barrier

        // ---- PV: o_acc[rt][dt] += P(32xkeys64) x Vt(d64 x keys64) ----
        short8 pf[2][2], vf[4][2];
#pragma unroll
        for (int rt = 0; rt < 2; rt++)
#pragma unroll
            for (int ks = 0; ks < 2; ks++)
                pf[rt][ks] = *(const short8*)(Ps + (w32 + rt * 16 + r) * KPAD + ks * 32 + q2 * 8);
#pragma unroll
        for (int dt = 0; dt < 4; dt++)
#pragma unroll
            for (int ks = 0; ks < 2; ks++)
                vf[dt][ks] = *(const short8*)(Vts + (dt * 16 + r) * KPAD + ks * 32 + q2 * 8);
#pragma unroll
        for (int rt = 0; rt < 2; rt++)
#pragma unroll
            for (int dt = 0; dt < 4; dt++)
#pragma unroll
                for (int ks = 0; ks < 2; ks++)
                    o_acc[rt][dt] = __builtin_amdgcn_mfma_f32_16x16x32_bf16(pf[rt][ks], vf[dt][ks], o_acc[rt][dt], 0, 0, 0);
    }

    // vals[b][s][h*64 + d]; lane col d = dt*16 + r, rows q2*4+reg
#pragma unroll
    for (int rt = 0; rt < 2; rt++) {
#pragma unroll
        for (int reg = 0; reg < 4; reg++) {
            float inv = 1.0f / l_i[rt][reg];
            int srow = q0 + w32 + rt * 16 + q2 * 4 + reg;
            size_t base = ((size_t)b * S_LEN + srow) * D_MODEL + h * HEAD_DIM + r;
#pragma unroll
            for (int dt = 0; dt < 4; dt++)
                vals[base + dt * 16] = f2b(o_acc[rt][dt][reg] * inv);
        }
    }
}

extern "C" void kernel_launch(void* const* d_in, const int* in_sizes, int n_in,
                              void* d_out, int out_size, void* d_ws, size_t ws_size,
                              hipStream_t stream) {
    const float* x    = (const float*)d_in[0];
    const float* Wqkv = (const float*)d_in[1];
    const float* bqkv = (const float*)d_in[2];
    const float* Wo   = (const float*)d_in[3];
    const float* bo   = (const float*)d_in[4];
    float* out = (float*)d_out;

    const size_t NX = 4194304, NW = 3145728, NO = 1048576;
    unsigned short* xb    = (unsigned short*)d_ws;
    unsigned short* Wqkvb = xb + NX;
    unsigned short* Wob   = Wqkvb + NW;
    unsigned short* Qb    = Wob + NO;
    unsigned short* Kb    = Qb + NX;
    unsigned short* Vb    = Kb + NX;      // [b,h,d,s]
    unsigned short* vals  = xb;           // reuse x region after qkv_gemm

    cvt3<<<4096, 256, 0, stream>>>(x, Wqkv, Wo, xb, Wqkvb, Wob,
                                   (int)(NX / 8), (int)(NW / 8), (int)(NO / 8));
    qkv_gemm<<<dim3(24, 32), 256, 0, stream>>>(xb, Wqkvb, bqkv, Qb, Kb, Vb);
    attn_kernel<<<dim3(16, 32), 256, 0, stream>>>(Qb, Kb, Vb, vals);
    out_gemm<<<dim3(8, 32), 256, 0, stream>>>(vals, Wob, bo, out);
}

// Round 6
// 273.533 us; speedup vs baseline: 2.9523x; 1.0671x over previous
//
#include <hip/hip_runtime.h>

// MHA: B=2, S=2048, D=1024, H=16, hd=64. Inputs/outputs FLOAT32 (per reference).
// k0: cvt x, Wqkv, Wo -> bf16 in ws
// k1: qkv GEMM (MFMA) -> Q(*0.125*log2e) [b,h,s,d], K [b,h,s,d], V^T [b,h,d,s]
// k2: MFMA flash attention, S^T orientation, 128-key tiles -> vals [B,S,D] bf16
// k3: out GEMM (MFMA) -> f32

typedef short short8 __attribute__((ext_vector_type(8)));
typedef unsigned short ushort8v __attribute__((ext_vector_type(8)));
typedef unsigned short ushort4v __attribute__((ext_vector_type(4)));
typedef float floatx4 __attribute__((ext_vector_type(4)));

#define S_LEN 2048
#define D_MODEL 1024
#define N_HEADS 16
#define HEAD_DIM 64

// attn LDS strides (shorts). All 16B multiples (b128-safe), non-pow2 rows.
#define QS_ST 72    // Qs[128][72]
#define KS_ST 72    // Ks[128][72]   (key-major, d inner)
#define VS_ST 136   // Vts[64][136]  (d-major, 128 keys inner)
#define PS_ST 72    // Ps[128][72]   (q-major, 64-key chunk inner)

// gfx950 native 2^x (v_exp_f32). HIP has no __exp2f; plain exp2f round-trips libm.
#define EXP2F(x) __builtin_amdgcn_exp2f(x)

__device__ inline float bf2f(unsigned int u16) {
    union { unsigned int i; float f; } v; v.i = u16 << 16; return v.f;
}
// f32 -> bf16 (RNE), bit-level.
__device__ inline unsigned short f2b(float f) {
    union { float f; unsigned int u; } v; v.f = f;
    return (unsigned short)((v.u + 0x7FFFu + ((v.u >> 16) & 1u)) >> 16);
}

// k0: convert three f32 arrays to bf16. Counts in groups of 8 elements.
__global__ __launch_bounds__(256)
void cvt3(const float* __restrict__ s0, const float* __restrict__ s1,
          const float* __restrict__ s2,
          unsigned short* __restrict__ d0, unsigned short* __restrict__ d1,
          unsigned short* __restrict__ d2,
          int n0, int n1, int n2) {
    const int total = n0 + n1 + n2;
    for (int g = blockIdx.x * blockDim.x + threadIdx.x; g < total;
         g += gridDim.x * blockDim.x) {
        const float* s; unsigned short* d; int l;
        if (g < n0)            { s = s0; d = d0; l = g; }
        else if (g < n0 + n1)  { s = s1; d = d1; l = g - n0; }
        else                   { s = s2; d = d2; l = g - n0 - n1; }
        const float4* sp = (const float4*)s + (size_t)l * 2;
        float4 f0 = sp[0], f1 = sp[1];
        ushort8v o;
        o[0] = f2b(f0.x); o[1] = f2b(f0.y); o[2] = f2b(f0.z); o[3] = f2b(f0.w);
        o[4] = f2b(f1.x); o[5] = f2b(f1.y); o[6] = f2b(f1.z); o[7] = f2b(f1.w);
        *(ushort8v*)(d + (size_t)l * 8) = o;
    }
}

// ---------------- MFMA GEMM core: C[m,n] = sum_k A[m,k] * W[n,k] --------------
__device__ inline void gemm_core(const unsigned short* __restrict__ A,
                                 const unsigned short* __restrict__ W,
                                 int m0, int n0, int K,
                                 unsigned short* As, unsigned short* Bs,
                                 floatx4 acc[4][4]) {
    const int tid  = threadIdx.x;
    const int lane = tid & 63;
    const int wave = tid >> 6;
    const int wm = wave >> 1, wn = wave & 1;
    const int r = lane & 15, q = lane >> 4;

    const int lrow  = tid >> 1;
    const int lhalf = (tid & 1) * 32;

    for (int k0 = 0; k0 < K; k0 += 64) {
        __syncthreads();
        const uint4* ga = (const uint4*)(A + (size_t)(m0 + lrow) * K + k0 + lhalf);
        const uint4* gb = (const uint4*)(W + (size_t)(n0 + lrow) * K + k0 + lhalf);
        uint4* sa = (uint4*)(As + lrow * 64 + lhalf);
        uint4* sb = (uint4*)(Bs + lrow * 64 + lhalf);
#pragma unroll
        for (int i = 0; i < 4; i++) { sa[i] = ga[i]; sb[i] = gb[i]; }
        __syncthreads();
#pragma unroll
        for (int kk = 0; kk < 64; kk += 32) {
            short8 aF[4], bF[4];
#pragma unroll
            for (int t = 0; t < 4; t++)
                aF[t] = *(const short8*)(As + (wm * 64 + t * 16 + r) * 64 + kk + q * 8);
#pragma unroll
            for (int t = 0; t < 4; t++)
                bF[t] = *(const short8*)(Bs + (wn * 64 + t * 16 + r) * 64 + kk + q * 8);
#pragma unroll
            for (int i = 0; i < 4; i++)
#pragma unroll
                for (int j = 0; j < 4; j++)
                    acc[i][j] = __builtin_amdgcn_mfma_f32_16x16x32_bf16(aF[i], bF[j], acc[i][j], 0, 0, 0);
        }
    }
}

// k1: QKV projection. Grid (24, 32). Q scaled by 0.125*log2(e) (exp2 softmax).
// Q,K layout [b,h,s,d]; V layout [b,h,d,s] (transposed for attn B-fragments).
__global__ __launch_bounds__(256)
void qkv_gemm(const unsigned short* __restrict__ x,
              const unsigned short* __restrict__ Wqkv,
              const float* __restrict__ bqkv,
              unsigned short* __restrict__ Qb,
              unsigned short* __restrict__ Kb,
              unsigned short* __restrict__ Vb) {
    __shared__ unsigned short As[128 * 64];
    __shared__ unsigned short Bs[128 * 64];
    const int lane = threadIdx.x & 63;
    const int wave = threadIdx.x >> 6;
    const int wm = wave >> 1, wn = wave & 1;
    const int r = lane & 15, q = lane >> 4;
    const int m0 = blockIdx.y * 128;
    const int n0 = blockIdx.x * 128;

    floatx4 acc[4][4] = {};
    gemm_core(x, Wqkv, m0, n0, D_MODEL, As, Bs, acc);

#pragma unroll
    for (int i = 0; i < 4; i++) {
#pragma unroll
        for (int j = 0; j < 4; j++) {
            int n = n0 + wn * 64 + j * 16 + r;            // h*192 + typ*64 + d
            int h = n / 192;
            int rem = n % 192;
            int typ = rem >> 6;                            // 0=Q 1=K 2=V
            int d = rem & 63;
            float bv = bqkv[n];
            int m = m0 + wm * 64 + i * 16 + q * 4;         // first of 4 rows
            int b = m >> 11, s = m & 2047;
            if (typ == 2) {
                ushort4v pk;
#pragma unroll
                for (int rg = 0; rg < 4; rg++) pk[rg] = f2b(acc[i][j][rg] + bv);
                *(ushort4v*)(Vb + ((size_t)((b * N_HEADS + h) * HEAD_DIM + d)) * S_LEN + s) = pk;
            } else {
                unsigned short* dst = (typ == 0) ? Qb : Kb;
                float sc = (typ == 0) ? 0.180336880f : 1.0f;  // 0.125*log2e
#pragma unroll
                for (int rg = 0; rg < 4; rg++)
                    dst[(((size_t)(b * N_HEADS + h)) * S_LEN + s + rg) * HEAD_DIM + d] =
                        f2b((acc[i][j][rg] + bv) * sc);
            }
        }
    }
}

// k3: output projection. Grid (8, 32). f32 output.
__global__ __launch_bounds__(256)
void out_gemm(const unsigned short* __restrict__ vals,
              const unsigned short* __restrict__ Wo,
              const float* __restrict__ bo,
              float* __restrict__ out) {
    __shared__ unsigned short As[128 * 64];
    __shared__ unsigned short Bs[128 * 64];
    const int lane = threadIdx.x & 63;
    const int wave = threadIdx.x >> 6;
    const int wm = wave >> 1, wn = wave & 1;
    const int r = lane & 15, q = lane >> 4;
    const int m0 = blockIdx.y * 128;
    const int n0 = blockIdx.x * 128;

    floatx4 acc[4][4] = {};
    gemm_core(vals, Wo, m0, n0, D_MODEL, As, Bs, acc);

#pragma unroll
    for (int i = 0; i < 4; i++) {
#pragma unroll
        for (int j = 0; j < 4; j++) {
            int n = n0 + wn * 64 + j * 16 + r;
            float bv = bo[n];
#pragma unroll
            for (int rg = 0; rg < 4; rg++) {
                int m = m0 + wm * 64 + i * 16 + q * 4 + rg;
                out[(size_t)m * D_MODEL + n] = acc[i][j][rg] + bv;
            }
        }
    }
}

// k2: MFMA flash attention, S^T orientation. Grid (S/128=16, B*H=32), 4 waves.
// Wave w owns q columns w*32..w*32+31 (2 n-tiles). K-tile = 128 keys (8 m-tiles).
// S^T = K x Q^T: C-layout col = q (lane&15), row = key (q2*4+reg). Softmax over
// keys is in-register tree + 2 shuffles. P store: packed b64 (regs = keys).
// PV (per 64-key chunk): A = P[q][key] from Ps, B = V^T[d][key] from Vts.
__global__ __launch_bounds__(256)
void attn_kernel(const unsigned short* __restrict__ Qb,
                 const unsigned short* __restrict__ Kb,
                 const unsigned short* __restrict__ Vg,   // [b,h,d,s]
                 unsigned short* __restrict__ vals) {
    __shared__ unsigned short Qs[128 * QS_ST];
    __shared__ unsigned short Ks[128 * KS_ST];
    __shared__ unsigned short Vts[64 * VS_ST];
    __shared__ unsigned short Ps[128 * PS_ST];

    const int tid = threadIdx.x;
    const int lane = tid & 63;
    const int wave = tid >> 6;
    const int r = lane & 15, q2 = lane >> 4;
    const int w32 = wave * 32;
    const int bh = blockIdx.y;
    const int b = bh >> 4, h = bh & 15;
    const int q0 = blockIdx.x * 128;

    const unsigned short* Qp = Qb + (size_t)bh * S_LEN * HEAD_DIM;
    const unsigned short* Kp = Kb + (size_t)bh * S_LEN * HEAD_DIM;
    const unsigned short* Vp = Vg + (size_t)bh * HEAD_DIM * S_LEN;

    // staging coords
    const int krow = tid >> 1, khalf = (tid & 1) * 32;   // K/Q: row, 32-elem half
    const int vrow = tid >> 2, vseg = (tid & 3) * 32;    // V^T: d row, 32-key seg

    // ---- stage Q (once) + K/V tile 0, then one barrier ----
    {
        const uint4* gq = (const uint4*)(Qp + (size_t)(q0 + krow) * HEAD_DIM + khalf);
        uint4* sq = (uint4*)(Qs + krow * QS_ST + khalf);
#pragma unroll
        for (int i = 0; i < 4; i++) sq[i] = gq[i];
        const uint4* gk = (const uint4*)(Kp + (size_t)krow * HEAD_DIM + khalf);
        uint4* sk = (uint4*)(Ks + krow * KS_ST + khalf);
#pragma unroll
        for (int i = 0; i < 4; i++) sk[i] = gk[i];
        const uint4* gv = (const uint4*)(Vp + (size_t)vrow * S_LEN + vseg);
        uint4* sv = (uint4*)(Vts + vrow * VS_ST + vseg);
#pragma unroll
        for (int i = 0; i < 4; i++) sv[i] = gv[i];
    }
    __syncthreads();

    // Q fragments (invariant): B-frag n = q = w32 + nt*16 + r
    short8 qf[2][2];
#pragma unroll
    for (int nt = 0; nt < 2; nt++)
#pragma unroll
        for (int ks = 0; ks < 2; ks++)
            qf[nt][ks] = *(const short8*)(Qs + (w32 + nt * 16 + r) * QS_ST + ks * 32 + q2 * 8);

    float m_i[2] = {-1e30f, -1e30f}, l_i[2] = {0.f, 0.f};
    floatx4 o_acc[2][4] = {};
    uint4 kreg[4], vreg[4];

    for (int kt = 0; kt < S_LEN; kt += 128) {
        const int more = (kt + 128 < S_LEN);
        if (more) {  // prefetch next tile into regs; drains during compute
            const uint4* gk = (const uint4*)(Kp + (size_t)(kt + 128 + krow) * HEAD_DIM + khalf);
            const uint4* gv = (const uint4*)(Vp + (size_t)vrow * S_LEN + kt + 128 + vseg);
#pragma unroll
            for (int i = 0; i < 4; i++) { kreg[i] = gk[i]; vreg[i] = gv[i]; }
        }

        // ---- S^T: sp[mt][nt], key = mt*16 + q2*4 + reg, q = w32 + nt*16 + r ----
        floatx4 sp[8][2] = {};
#pragma unroll
        for (int mt = 0; mt < 8; mt++)
#pragma unroll
            for (int ks = 0; ks < 2; ks++) {
                short8 kfr = *(const short8*)(Ks + (mt * 16 + r) * KS_ST + ks * 32 + q2 * 8);
#pragma unroll
                for (int nt = 0; nt < 2; nt++)
                    sp[mt][nt] = __builtin_amdgcn_mfma_f32_16x16x32_bf16(kfr, qf[nt][ks], sp[mt][nt], 0, 0, 0);
            }

        // ---- online softmax over 128 keys (per q column) ----
        float alpha_s[2];
#pragma unroll
        for (int nt = 0; nt < 2; nt++) {
            floatx4 vm = sp[0][nt];
#pragma unroll
            for (int mt = 1; mt < 8; mt++) {
                vm[0] = fmaxf(vm[0], sp[mt][nt][0]); vm[1] = fmaxf(vm[1], sp[mt][nt][1]);
                vm[2] = fmaxf(vm[2], sp[mt][nt][2]); vm[3] = fmaxf(vm[3], sp[mt][nt][3]);
            }
            float mx = fmaxf(fmaxf(vm[0], vm[1]), fmaxf(vm[2], vm[3]));
            mx = fmaxf(mx, __shfl_xor(mx, 16, 64));
            mx = fmaxf(mx, __shfl_xor(mx, 32, 64));
            float nm = fmaxf(m_i[nt], mx);
            alpha_s[nt] = EXP2F(m_i[nt] - nm);
            m_i[nt] = nm;
            float rs = 0.f;
#pragma unroll
            for (int mt = 0; mt < 8; mt++)
#pragma unroll
                for (int reg = 0; reg < 4; reg++) {
                    float e = EXP2F(sp[mt][nt][reg] - nm);
                    sp[mt][nt][reg] = e;
                    rs += e;
                }
            rs += __shfl_xor(rs, 16, 64);
            rs += __shfl_xor(rs, 32, 64);
            l_i[nt] = l_i[nt] * alpha_s[nt] + rs;
        }

        // ---- rescale o_acc: alpha for row q2*4+reg lives in lane r=q2*4+reg ----
#pragma unroll
        for (int nt = 0; nt < 2; nt++)
#pragma unroll
            for (int reg = 0; reg < 4; reg++) {
                float a = __shfl(alpha_s[nt], q2 * 4 + reg, 64);
#pragma unroll
                for (int dt = 0; dt < 4; dt++) o_acc[nt][dt][reg] *= a;
            }

        // ---- PV in two 64-key chunks through Ps (same-wave LDS round trip) ----
#pragma unroll
        for (int c = 0; c < 2; c++) {
#pragma unroll
            for (int nt = 0; nt < 2; nt++)
#pragma unroll
                for (int ml = 0; ml < 4; ml++) {
                    int mt = c * 4 + ml;
                    ushort4v pk;
#pragma unroll
                    for (int reg = 0; reg < 4; reg++) pk[reg] = f2b(sp[mt][nt][reg]);
                    *(ushort4v*)(Ps + (w32 + nt * 16 + r) * PS_ST + ml * 16 + q2 * 4) = pk;
                }
            short8 pf[2][2], vf[4][2];
#pragma unroll
            for (int nt = 0; nt < 2; nt++)
#pragma unroll
                for (int ks = 0; ks < 2; ks++)
                    pf[nt][ks] = *(const short8*)(Ps + (w32 + nt * 16 + r) * PS_ST + ks * 32 + q2 * 8);
#pragma unroll
            for (int dt = 0; dt < 4; dt++)
#pragma unroll
                for (int ks = 0; ks < 2; ks++)
                    vf[dt][ks] = *(const short8*)(Vts + (dt * 16 + r) * VS_ST + c * 64 + ks * 32 + q2 * 8);
#pragma unroll
            for (int nt = 0; nt < 2; nt++)
#pragma unroll
                for (int dt = 0; dt < 4; dt++)
#pragma unroll
                    for (int ks = 0; ks < 2; ks++)
                        o_acc[nt][dt] = __builtin_amdgcn_mfma_f32_16x16x32_bf16(pf[nt][ks], vf[dt][ks], o_acc[nt][dt], 0, 0, 0);
        }

        if (more) {
            __syncthreads();   // all waves done reading Ks/Vts of tile kt
            uint4* sk = (uint4*)(Ks + krow * KS_ST + khalf);
            uint4* sv = (uint4*)(Vts + vrow * VS_ST + vseg);
#pragma unroll
            for (int i = 0; i < 4; i++) { sk[i] = kreg[i]; sv[i] = vreg[i]; }
            __syncthreads();   // tile kt+128 visible
        }
    }

    // ---- output: rows q = q2*4+reg within tile; 1/l from lane r = q2*4+reg ----
#pragma unroll
    for (int nt = 0; nt < 2; nt++) {
#pragma unroll
        for (int reg = 0; reg < 4; reg++) {
            float inv = 1.0f / __shfl(l_i[nt], q2 * 4 + reg, 64);
            int srow = q0 + w32 + nt * 16 + q2 * 4 + reg;
            size_t base = ((size_t)b * S_LEN + srow) * D_MODEL + h * HEAD_DIM + r;
#pragma unroll
            for (int dt = 0; dt < 4; dt++)
                vals[base + dt * 16] = f2b(o_acc[nt][dt][reg] * inv);
        }
    }
}

extern "C" void kernel_launch(void* const* d_in, const int* in_sizes, int n_in,
                              void* d_out, int out_size, void* d_ws, size_t ws_size,
                              hipStream_t stream) {
    const float* x    = (const float*)d_in[0];
    const float* Wqkv = (const float*)d_in[1];
    const float* bqkv = (const float*)d_in[2];
    const float* Wo   = (const float*)d_in[3];
    const float* bo   = (const float*)d_in[4];
    float* out = (float*)d_out;

    const size_t NX = 4194304, NW = 3145728, NO = 1048576;
    unsigned short* xb    = (unsigned short*)d_ws;
    unsigned short* Wqkvb = xb + NX;
    unsigned short* Wob   = Wqkvb + NW;
    unsigned short* Qb    = Wob + NO;
    unsigned short* Kb    = Qb + NX;
    unsigned short* Vb    = Kb + NX;      // [b,h,d,s]
    unsigned short* vals  = xb;           // reuse x region after qkv_gemm

    cvt3<<<4096, 256, 0, stream>>>(x, Wqkv, Wo, xb, Wqkvb, Wob,
                                   (int)(NX / 8), (int)(NW / 8), (int)(NO / 8));
    qkv_gemm<<<dim3(24, 32), 256, 0, stream>>>(xb, Wqkvb, bqkv, Qb, Kb, Vb);
    attn_kernel<<<dim3(16, 32), 256, 0, stream>>>(Qb, Kb, Vb, vals);
    out_gemm<<<dim3(8, 32), 256, 0, stream>>>(vals, Wob, bo, out);
}

// Round 7
// 270.363 us; speedup vs baseline: 2.9869x; 1.0117x over previous
//
#include <hip/hip_runtime.h>

// MHA: B=2, S=2048, D=1024, H=16, hd=64. Inputs/outputs FLOAT32 (per reference).
// k0: cvt x, Wqkv, Wo -> bf16 in ws
// k1: qkv GEMM (MFMA) -> Q(*0.125*log2e) [b,h,s,d], K [b,h,s,d], V^T [b,h,d,s]
// k2: MFMA flash attention, S^T orientation, 64-key tiles, spill-free -> vals bf16
// k3: out GEMM (MFMA) -> f32

typedef short short8 __attribute__((ext_vector_type(8)));
typedef unsigned short ushort8v __attribute__((ext_vector_type(8)));
typedef unsigned short ushort4v __attribute__((ext_vector_type(4)));
typedef float floatx4 __attribute__((ext_vector_type(4)));

#define S_LEN 2048
#define D_MODEL 1024
#define N_HEADS 16
#define HEAD_DIM 64

// attn LDS row stride (shorts): 72 -> 144 B = 9*16 B, so every 16B-aligned col
// offset stays b128-safe at any row; non-pow2 breaks bank patterns.
#define AST 72

// gfx950 native 2^x (v_exp_f32). HIP has no __exp2f; plain exp2f round-trips libm.
#define EXP2F(x) __builtin_amdgcn_exp2f(x)

__device__ inline float bf2f(unsigned int u16) {
    union { unsigned int i; float f; } v; v.i = u16 << 16; return v.f;
}
// f32 -> bf16 (RNE), bit-level.
__device__ inline unsigned short f2b(float f) {
    union { float f; unsigned int u; } v; v.f = f;
    return (unsigned short)((v.u + 0x7FFFu + ((v.u >> 16) & 1u)) >> 16);
}
__device__ inline unsigned int fbits(float f) {
    union { float f; unsigned int u; } v; v.f = f; return v.u;
}
// pack two f32 -> bf16x2 (round-half-up): high halves of biased values.
__device__ inline unsigned int pack_bf2(float lo, float hi) {
    return __byte_perm(fbits(lo) + 0x8000u, fbits(hi) + 0x8000u, 0x7632);
}

// k0: convert three f32 arrays to bf16. Counts in groups of 8 elements.
__global__ __launch_bounds__(256)
void cvt3(const float* __restrict__ s0, const float* __restrict__ s1,
          const float* __restrict__ s2,
          unsigned short* __restrict__ d0, unsigned short* __restrict__ d1,
          unsigned short* __restrict__ d2,
          int n0, int n1, int n2) {
    const int total = n0 + n1 + n2;
    for (int g = blockIdx.x * blockDim.x + threadIdx.x; g < total;
         g += gridDim.x * blockDim.x) {
        const float* s; unsigned short* d; int l;
        if (g < n0)            { s = s0; d = d0; l = g; }
        else if (g < n0 + n1)  { s = s1; d = d1; l = g - n0; }
        else                   { s = s2; d = d2; l = g - n0 - n1; }
        const float4* sp = (const float4*)s + (size_t)l * 2;
        float4 f0 = sp[0], f1 = sp[1];
        ushort8v o;
        o[0] = f2b(f0.x); o[1] = f2b(f0.y); o[2] = f2b(f0.z); o[3] = f2b(f0.w);
        o[4] = f2b(f1.x); o[5] = f2b(f1.y); o[6] = f2b(f1.z); o[7] = f2b(f1.w);
        *(ushort8v*)(d + (size_t)l * 8) = o;
    }
}

// ---------------- MFMA GEMM core: C[m,n] = sum_k A[m,k] * W[n,k] --------------
__device__ inline void gemm_core(const unsigned short* __restrict__ A,
                                 const unsigned short* __restrict__ W,
                                 int m0, int n0, int K,
                                 unsigned short* As, unsigned short* Bs,
                                 floatx4 acc[4][4]) {
    const int tid  = threadIdx.x;
    const int lane = tid & 63;
    const int wave = tid >> 6;
    const int wm = wave >> 1, wn = wave & 1;
    const int r = lane & 15, q = lane >> 4;

    const int lrow  = tid >> 1;
    const int lhalf = (tid & 1) * 32;

    for (int k0 = 0; k0 < K; k0 += 64) {
        __syncthreads();
        const uint4* ga = (const uint4*)(A + (size_t)(m0 + lrow) * K + k0 + lhalf);
        const uint4* gb = (const uint4*)(W + (size_t)(n0 + lrow) * K + k0 + lhalf);
        uint4* sa = (uint4*)(As + lrow * 64 + lhalf);
        uint4* sb = (uint4*)(Bs + lrow * 64 + lhalf);
#pragma unroll
        for (int i = 0; i < 4; i++) { sa[i] = ga[i]; sb[i] = gb[i]; }
        __syncthreads();
#pragma unroll
        for (int kk = 0; kk < 64; kk += 32) {
            short8 aF[4], bF[4];
#pragma unroll
            for (int t = 0; t < 4; t++)
                aF[t] = *(const short8*)(As + (wm * 64 + t * 16 + r) * 64 + kk + q * 8);
#pragma unroll
            for (int t = 0; t < 4; t++)
                bF[t] = *(const short8*)(Bs + (wn * 64 + t * 16 + r) * 64 + kk + q * 8);
#pragma unroll
            for (int i = 0; i < 4; i++)
#pragma unroll
                for (int j = 0; j < 4; j++)
                    acc[i][j] = __builtin_amdgcn_mfma_f32_16x16x32_bf16(aF[i], bF[j], acc[i][j], 0, 0, 0);
        }
    }
}

// k1: QKV projection. Grid (24, 32). Q scaled by 0.125*log2(e) (exp2 softmax).
// Q,K layout [b,h,s,d]; V layout [b,h,d,s] (transposed for attn B-fragments).
__global__ __launch_bounds__(256)
void qkv_gemm(const unsigned short* __restrict__ x,
              const unsigned short* __restrict__ Wqkv,
              const float* __restrict__ bqkv,
              unsigned short* __restrict__ Qb,
              unsigned short* __restrict__ Kb,
              unsigned short* __restrict__ Vb) {
    __shared__ unsigned short As[128 * 64];
    __shared__ unsigned short Bs[128 * 64];
    const int lane = threadIdx.x & 63;
    const int wave = threadIdx.x >> 6;
    const int wm = wave >> 1, wn = wave & 1;
    const int r = lane & 15, q = lane >> 4;
    const int m0 = blockIdx.y * 128;
    const int n0 = blockIdx.x * 128;

    floatx4 acc[4][4] = {};
    gemm_core(x, Wqkv, m0, n0, D_MODEL, As, Bs, acc);

#pragma unroll
    for (int i = 0; i < 4; i++) {
#pragma unroll
        for (int j = 0; j < 4; j++) {
            int n = n0 + wn * 64 + j * 16 + r;            // h*192 + typ*64 + d
            int h = n / 192;
            int rem = n % 192;
            int typ = rem >> 6;                            // 0=Q 1=K 2=V
            int d = rem & 63;
            float bv = bqkv[n];
            int m = m0 + wm * 64 + i * 16 + q * 4;         // first of 4 rows
            int b = m >> 11, s = m & 2047;
            if (typ == 2) {
                ushort4v pk;
#pragma unroll
                for (int rg = 0; rg < 4; rg++) pk[rg] = f2b(acc[i][j][rg] + bv);
                *(ushort4v*)(Vb + ((size_t)((b * N_HEADS + h) * HEAD_DIM + d)) * S_LEN + s) = pk;
            } else {
                unsigned short* dst = (typ == 0) ? Qb : Kb;
                float sc = (typ == 0) ? 0.180336880f : 1.0f;  // 0.125*log2e
#pragma unroll
                for (int rg = 0; rg < 4; rg++)
                    dst[(((size_t)(b * N_HEADS + h)) * S_LEN + s + rg) * HEAD_DIM + d] =
                        f2b((acc[i][j][rg] + bv) * sc);
            }
        }
    }
}

// k3: output projection. Grid (8, 32). f32 output.
__global__ __launch_bounds__(256)
void out_gemm(const unsigned short* __restrict__ vals,
              const unsigned short* __restrict__ Wo,
              const float* __restrict__ bo,
              float* __restrict__ out) {
    __shared__ unsigned short As[128 * 64];
    __shared__ unsigned short Bs[128 * 64];
    const int lane = threadIdx.x & 63;
    const int wave = threadIdx.x >> 6;
    const int wm = wave >> 1, wn = wave & 1;
    const int r = lane & 15, q = lane >> 4;
    const int m0 = blockIdx.y * 128;
    const int n0 = blockIdx.x * 128;

    floatx4 acc[4][4] = {};
    gemm_core(vals, Wo, m0, n0, D_MODEL, As, Bs, acc);

#pragma unroll
    for (int i = 0; i < 4; i++) {
#pragma unroll
        for (int j = 0; j < 4; j++) {
            int n = n0 + wn * 64 + j * 16 + r;
            float bv = bo[n];
#pragma unroll
            for (int rg = 0; rg < 4; rg++) {
                int m = m0 + wm * 64 + i * 16 + q * 4 + rg;
                out[(size_t)m * D_MODEL + n] = acc[i][j][rg] + bv;
            }
        }
    }
}

// k2: MFMA flash attention, S^T orientation, 64-key tiles, spill-free.
// Grid: 512 blocks 1D, XCD-swizzled: xcd=idx&7 -> 4 consecutive bh per XCD so
// each XCD's L2 holds its K/V working set (2 MB). 4 waves x 32 q-cols = 128 q.
// S^T = K x Q^T: C col = q (lane&15), row = key (q2*4+reg + mt*16). P round-trips
// through LDS overlaid on Qs (Q lives in regs; each wave's P rows = its Q rows).
__global__ __launch_bounds__(256, 2)
void attn_kernel(const unsigned short* __restrict__ Qb,
                 const unsigned short* __restrict__ Kb,
                 const unsigned short* __restrict__ Vg,   // [b,h,d,s]
                 unsigned short* __restrict__ vals) {
    __shared__ unsigned short QPs[128 * AST];  // Q staging, then P
    __shared__ unsigned short Ks[64 * AST];
    __shared__ unsigned short Vts[64 * AST];

    const int tid = threadIdx.x;
    const int lane = tid & 63;
    const int wave = tid >> 6;
    const int r = lane & 15, q2 = lane >> 4;
    const int w32 = wave * 32;

    const int idx  = blockIdx.x;
    const int xcd  = idx & 7;
    const int slot = idx >> 3;                 // 0..63
    const int bh   = (xcd << 2) | (slot >> 4); // 4 bh per XCD
    const int q0   = (slot & 15) * 128;
    const int b = bh >> 4, h = bh & 15;

    const unsigned short* Qp = Qb + (size_t)bh * S_LEN * HEAD_DIM;
    const unsigned short* Kp = Kb + (size_t)bh * S_LEN * HEAD_DIM;
    const unsigned short* Vp = Vg + (size_t)bh * HEAD_DIM * S_LEN;

    const int qrow = tid >> 1, qhalf = (tid & 1) * 32;   // Q staging
    const int krow = tid >> 2, kseg = (tid & 3) * 16;    // K/V^T staging

    // ---- prologue: stage Q (wave-local rows) + K/V tile 0 ----
    {
        const uint4* gq = (const uint4*)(Qp + (size_t)(q0 + qrow) * HEAD_DIM + qhalf);
        uint4* sq = (uint4*)(QPs + qrow * AST + qhalf);
#pragma unroll
        for (int i = 0; i < 4; i++) sq[i] = gq[i];
        const uint4* gk = (const uint4*)(Kp + (size_t)krow * HEAD_DIM + kseg);
        uint4* sk = (uint4*)(Ks + krow * AST + kseg);
        sk[0] = gk[0]; sk[1] = gk[1];
        const uint4* gv = (const uint4*)(Vp + (size_t)krow * S_LEN + kseg);
        uint4* sv = (uint4*)(Vts + krow * AST + kseg);
        sv[0] = gv[0]; sv[1] = gv[1];
    }
    __syncthreads();

    // Q fragments (held in regs for the whole kernel); QPs becomes Ps after this.
    short8 qf[2][2];
#pragma unroll
    for (int nt = 0; nt < 2; nt++)
#pragma unroll
        for (int ks = 0; ks < 2; ks++)
            qf[nt][ks] = *(const short8*)(QPs + (w32 + nt * 16 + r) * AST + ks * 32 + q2 * 8);

    float m_i[2] = {-1e30f, -1e30f}, l_i[2] = {0.f, 0.f};
    floatx4 o_acc[2][4] = {};
    uint4 kreg[2], vreg[2];

    for (int kt = 0; kt < S_LEN; kt += 64) {
        const int more = (kt + 64 < S_LEN);
        if (more) {  // register prefetch of next K/V tile; drains during compute
            const uint4* gk = (const uint4*)(Kp + (size_t)(kt + 64 + krow) * HEAD_DIM + kseg);
            const uint4* gv = (const uint4*)(Vp + (size_t)krow * S_LEN + kt + 64 + kseg);
            kreg[0] = gk[0]; kreg[1] = gk[1];
            vreg[0] = gv[0]; vreg[1] = gv[1];
        }

        // ---- S^T: sp[mt][nt]; key = mt*16 + q2*4 + reg, q-col = w32 + nt*16 + r
        floatx4 sp[4][2] = {};
#pragma unroll
        for (int mt = 0; mt < 4; mt++)
#pragma unroll
            for (int ks = 0; ks < 2; ks++) {
                short8 kfr = *(const short8*)(Ks + (mt * 16 + r) * AST + ks * 32 + q2 * 8);
#pragma unroll
                for (int nt = 0; nt < 2; nt++)
                    sp[mt][nt] = __builtin_amdgcn_mfma_f32_16x16x32_bf16(kfr, qf[nt][ks], sp[mt][nt], 0, 0, 0);
            }

        // ---- online softmax over 64 keys (per q column) ----
        float alpha_s[2];
#pragma unroll
        for (int nt = 0; nt < 2; nt++) {
            floatx4 vm = sp[0][nt];
#pragma unroll
            for (int mt = 1; mt < 4; mt++) {
                vm[0] = fmaxf(vm[0], sp[mt][nt][0]); vm[1] = fmaxf(vm[1], sp[mt][nt][1]);
                vm[2] = fmaxf(vm[2], sp[mt][nt][2]); vm[3] = fmaxf(vm[3], sp[mt][nt][3]);
            }
            float mx = fmaxf(fmaxf(vm[0], vm[1]), fmaxf(vm[2], vm[3]));
            mx = fmaxf(mx, __shfl_xor(mx, 16, 64));
            mx = fmaxf(mx, __shfl_xor(mx, 32, 64));
            float nm = fmaxf(m_i[nt], mx);
            alpha_s[nt] = EXP2F(m_i[nt] - nm);
            m_i[nt] = nm;
            float rs = 0.f;
#pragma unroll
            for (int mt = 0; mt < 4; mt++)
#pragma unroll
                for (int reg = 0; reg < 4; reg++) {
                    float e = EXP2F(sp[mt][nt][reg] - nm);
                    sp[mt][nt][reg] = e;
                    rs += e;
                }
            rs += __shfl_xor(rs, 16, 64);
            rs += __shfl_xor(rs, 32, 64);
            l_i[nt] = l_i[nt] * alpha_s[nt] + rs;
        }

        // ---- rescale o_acc (alpha for q-row q2*4+reg lives in lane r=q2*4+reg)
#pragma unroll
        for (int nt = 0; nt < 2; nt++)
#pragma unroll
            for (int reg = 0; reg < 4; reg++) {
                float a = __shfl(alpha_s[nt], q2 * 4 + reg, 64);
#pragma unroll
                for (int dt = 0; dt < 4; dt++) o_acc[nt][dt][reg] *= a;
            }

        // ---- P -> Ps (packed b64 stores; regs = consecutive keys) ----
#pragma unroll
        for (int nt = 0; nt < 2; nt++)
#pragma unroll
            for (int mt = 0; mt < 4; mt++) {
                uint2 pk;
                pk.x = pack_bf2(sp[mt][nt][0], sp[mt][nt][1]);
                pk.y = pack_bf2(sp[mt][nt][2], sp[mt][nt][3]);
                *(uint2*)(QPs + (w32 + nt * 16 + r) * AST + mt * 16 + q2 * 4) = pk;
            }

        // ---- PV: o_acc[nt][dt] += P(32q x 64k) x V^T(64d x 64k) ----
        short8 pf[2][2], vf[4][2];
#pragma unroll
        for (int nt = 0; nt < 2; nt++)
#pragma unroll
            for (int ks = 0; ks < 2; ks++)
                pf[nt][ks] = *(const short8*)(QPs + (w32 + nt * 16 + r) * AST + ks * 32 + q2 * 8);
#pragma unroll
        for (int dt = 0; dt < 4; dt++)
#pragma unroll
            for (int ks = 0; ks < 2; ks++)
                vf[dt][ks] = *(const short8*)(Vts + (dt * 16 + r) * AST + ks * 32 + q2 * 8);
#pragma unroll
        for (int nt = 0; nt < 2; nt++)
#pragma unroll
            for (int dt = 0; dt < 4; dt++)
#pragma unroll
                for (int ks = 0; ks < 2; ks++)
                    o_acc[nt][dt] = __builtin_amdgcn_mfma_f32_16x16x32_bf16(pf[nt][ks], vf[dt][ks], o_acc[nt][dt], 0, 0, 0);

        if (more) {
            __syncthreads();   // all waves done reading Ks/Vts of tile kt
            uint4* sk = (uint4*)(Ks + krow * AST + kseg);
            uint4* sv = (uint4*)(Vts + krow * AST + kseg);
            sk[0] = kreg[0]; sk[1] = kreg[1];
            sv[0] = vreg[0]; sv[1] = vreg[1];
            __syncthreads();   // tile kt+64 visible
        }
    }

    // ---- output: q-row = q2*4+reg within n-tile; 1/l from lane r=q2*4+reg ----
#pragma unroll
    for (int nt = 0; nt < 2; nt++) {
#pragma unroll
        for (int reg = 0; reg < 4; reg++) {
            float inv = 1.0f / __shfl(l_i[nt], q2 * 4 + reg, 64);
            int srow = q0 + w32 + nt * 16 + q2 * 4 + reg;
            size_t base = ((size_t)b * S_LEN + srow) * D_MODEL + h * HEAD_DIM + r;
#pragma unroll
            for (int dt = 0; dt < 4; dt++)
                vals[base + dt * 16] = f2b(o_acc[nt][dt][reg] * inv);
        }
    }
}

extern "C" void kernel_launch(void* const* d_in, const int* in_sizes, int n_in,
                              void* d_out, int out_size, void* d_ws, size_t ws_size,
                              hipStream_t stream) {
    const float* x    = (const float*)d_in[0];
    const float* Wqkv = (const float*)d_in[1];
    const float* bqkv = (const float*)d_in[2];
    const float* Wo   = (const float*)d_in[3];
    const float* bo   = (const float*)d_in[4];
    float* out = (float*)d_out;

    const size_t NX = 4194304, NW = 3145728, NO = 1048576;
    unsigned short* xb    = (unsigned short*)d_ws;
    unsigned short* Wqkvb = xb + NX;
    unsigned short* Wob   = Wqkvb + NW;
    unsigned short* Qb    = Wob + NO;
    unsigned short* Kb    = Qb + NX;
    unsigned short* Vb    = Kb + NX;      // [b,h,d,s]
    unsigned short* vals  = xb;           // reuse x region after qkv_gemm

    cvt3<<<4096, 256, 0, stream>>>(x, Wqkv, Wo, xb, Wqkvb, Wob,
                                   (int)(NX / 8), (int)(NW / 8), (int)(NO / 8));
    qkv_gemm<<<dim3(24, 32), 256, 0, stream>>>(xb, Wqkvb, bqkv, Qb, Kb, Vb);
    attn_kernel<<<512, 256, 0, stream>>>(Qb, Kb, Vb, vals);
    out_gemm<<<dim3(8, 32), 256, 0, stream>>>(vals, Wob, bo, out);
}